// Round 3
// baseline (663.835 us; speedup 1.0000x reference)
//
#include <hip/hip_runtime.h>
#include <hip/hip_bf16.h>

#define F 128
#define SLABS 8
#define SF 16   // feats per slab

static __device__ __forceinline__ unsigned short f2bf(float f) {
    unsigned int u = __float_as_uint(f);
    unsigned int r = (u + 0x7fffu + ((u >> 16) & 1u)) >> 16;   // RTN-even
    return (unsigned short)r;
}

#define BF2X(p) __uint_as_float((p) << 16)
#define BF2Y(p) __uint_as_float((p) & 0xffff0000u)

// ---------------- CSR build ----------------

__global__ void count_edges_k(const int* __restrict__ col, int* __restrict__ cnt, int E) {
    int e0 = (blockIdx.x * 256 + threadIdx.x) * 4;
    if (e0 + 4 <= E) {
        int4 c = *(const int4*)&col[e0];
        atomicAdd(&cnt[c.x], 1);
        atomicAdd(&cnt[c.y], 1);
        atomicAdd(&cnt[c.z], 1);
        atomicAdd(&cnt[c.w], 1);
    } else {
        for (int e = e0; e < E; e++) atomicAdd(&cnt[col[e]], 1);
    }
}

__global__ void scan1_k(const int* __restrict__ cnt, int* __restrict__ offs,
                        float* __restrict__ dinv, int* __restrict__ bsum, int n) {
    __shared__ int s[1024];
    int tid = threadIdx.x;
    int i = blockIdx.x * 1024 + tid;
    int v = (i < n) ? cnt[i] : 0;
    s[tid] = v;
    __syncthreads();
    for (int off = 1; off < 1024; off <<= 1) {
        int t = (tid >= off) ? s[tid - off] : 0;
        __syncthreads();
        s[tid] += t;
        __syncthreads();
    }
    if (i < n) {
        offs[i] = s[tid] - v;
        dinv[i] = rsqrtf((float)(v + 1));
    }
    if (tid == 1023) bsum[blockIdx.x] = s[1023];
}

__global__ void scan2_k(int* bsum, int nb) {
    __shared__ int s[128];
    int tid = threadIdx.x;
    int v = (tid < nb) ? bsum[tid] : 0;
    s[tid] = v;
    __syncthreads();
    for (int off = 1; off < 128; off <<= 1) {
        int t = (tid >= off) ? s[tid - off] : 0;
        __syncthreads();
        s[tid] += t;
        __syncthreads();
    }
    if (tid < nb) bsum[tid] = s[tid] - v;
}

__global__ void scan3_k(int* __restrict__ offs, int* __restrict__ cursor,
                        const int* __restrict__ bsum, int n, int E) {
    int i = blockIdx.x * 1024 + threadIdx.x;
    if (i < n) {
        int o = offs[i] + bsum[blockIdx.x];
        offs[i] = o;
        cursor[i] = o;
    }
    if (i == n) offs[n] = E;
}

__global__ void fill_k(const int* __restrict__ row, const int* __restrict__ col,
                       int* __restrict__ cursor, int* __restrict__ src, int E) {
    int e = blockIdx.x * 256 + threadIdx.x;
    if (e < E) {
        int v = col[e];
        int pos = atomicAdd(&cursor[v], 1);
        src[pos] = row[e];
    }
}

// ---------------- GEMM: Yslab[p][r][16] = bf16( dinv[r] * (X[r,:] @ W) ) ----------------
// BF16IN=0: X is f32 row-major [n][128]. BF16IN=1: X is bf16 slab-major [8][n][16].

template <int BF16IN>
__global__ __launch_bounds__(256) void gemm_scale_k(const void* __restrict__ Xin,
                                                    const float* __restrict__ W,
                                                    const float* __restrict__ dinv,
                                                    unsigned short* __restrict__ Ybf, int n) {
    __shared__ float Ws[F * F];   // 64 KB
    for (int i = threadIdx.x; i < F * F; i += 256) Ws[i] = W[i];
    __syncthreads();

    int lane = threadIdx.x & 31;
    int rg = threadIdx.x >> 5;
    int jc = lane * 4;
    int r0 = blockIdx.x * 64 + rg * 8;

    const float* Xf = (const float*)Xin;
    const unsigned short* Xh = (const unsigned short*)Xin;

    float4 acc[8];
    int rr[8];
#pragma unroll
    for (int i = 0; i < 8; i++) {
        acc[i] = make_float4(0.f, 0.f, 0.f, 0.f);
        int r = r0 + i;
        rr[i] = (r > n - 1) ? (n - 1) : r;
    }

    for (int k = 0; k < F; k += 4) {
        float4 w0 = *(const float4*)&Ws[(k + 0) * F + jc];
        float4 w1 = *(const float4*)&Ws[(k + 1) * F + jc];
        float4 w2 = *(const float4*)&Ws[(k + 2) * F + jc];
        float4 w3 = *(const float4*)&Ws[(k + 3) * F + jc];
#pragma unroll
        for (int i = 0; i < 8; i++) {
            float x0, x1, x2, x3;
            if (BF16IN) {
                const unsigned short* p = Xh + ((size_t)(k >> 4) * n + rr[i]) * SF + (k & 15);
                uint2 v = *(const uint2*)p;
                x0 = BF2X(v.x); x1 = BF2Y(v.x);
                x2 = BF2X(v.y); x3 = BF2Y(v.y);
            } else {
                float4 xv = *(const float4*)&Xf[(size_t)rr[i] * F + k];
                x0 = xv.x; x1 = xv.y; x2 = xv.z; x3 = xv.w;
            }
            acc[i].x = fmaf(x0, w0.x, acc[i].x); acc[i].y = fmaf(x0, w0.y, acc[i].y);
            acc[i].z = fmaf(x0, w0.z, acc[i].z); acc[i].w = fmaf(x0, w0.w, acc[i].w);
            acc[i].x = fmaf(x1, w1.x, acc[i].x); acc[i].y = fmaf(x1, w1.y, acc[i].y);
            acc[i].z = fmaf(x1, w1.z, acc[i].z); acc[i].w = fmaf(x1, w1.w, acc[i].w);
            acc[i].x = fmaf(x2, w2.x, acc[i].x); acc[i].y = fmaf(x2, w2.y, acc[i].y);
            acc[i].z = fmaf(x2, w2.z, acc[i].z); acc[i].w = fmaf(x2, w2.w, acc[i].w);
            acc[i].x = fmaf(x3, w3.x, acc[i].x); acc[i].y = fmaf(x3, w3.y, acc[i].y);
            acc[i].z = fmaf(x3, w3.z, acc[i].z); acc[i].w = fmaf(x3, w3.w, acc[i].w);
        }
    }

    int sp = jc >> 4;          // slab of this col group
    int j = jc & 15;
#pragma unroll
    for (int i = 0; i < 8; i++) {
        int r = r0 + i;
        if (r < n) {
            float s = dinv[r];
            unsigned long long pk =
                (unsigned long long)f2bf(s * acc[i].x) |
                ((unsigned long long)f2bf(s * acc[i].y) << 16) |
                ((unsigned long long)f2bf(s * acc[i].z) << 32) |
                ((unsigned long long)f2bf(s * acc[i].w) << 48);
            __builtin_nontemporal_store(pk,
                (unsigned long long*)&Ybf[((size_t)sp * n + r) * SF + j]);
        }
    }
}

// ---------------- Aggregation: XCD-pinned feature slabs ----------------
// block b: slab = b & 7 (XCD-pinned via round-robin dispatch), nodes = (b>>3)*32 .. +32
// 8-lane group per node, uint (2 bf16 feats) per lane -> 32 B/edge, L2-resident slab.

template <int WRITE_H>
__global__ __launch_bounds__(256) void agg_k(const unsigned short* __restrict__ Ybf,
                                             const float* __restrict__ dinv,
                                             const int* __restrict__ offs,
                                             const int* __restrict__ src,
                                             const float* __restrict__ bias,
                                             unsigned short* __restrict__ Hbf,
                                             float* __restrict__ gacc, int n) {
    int slab = blockIdx.x & 7;
    int nb = blockIdx.x >> 3;
    int grp = threadIdx.x >> 3;        // 0..31
    int l8 = threadIdx.x & 7;          // 0..7
    int g = nb * 32 + grp;
    const unsigned short* yb = Ybf + (size_t)slab * n * SF;
    int c2 = l8 * 2;

    float hx = 0.f, hy = 0.f;
    if (g < n) {
        unsigned int ps = *(const unsigned int*)&yb[(size_t)g * SF + c2];   // self-loop
        float ax0 = BF2X(ps), ay0 = BF2Y(ps);
        float ax1 = 0.f, ay1 = 0.f;

        int s = offs[g], e = offs[g + 1];
        int i = s;
        for (; i + 2 <= e; i += 2) {
            int u0 = src[i], u1 = src[i + 1];
            unsigned int p0 = *(const unsigned int*)&yb[(size_t)u0 * SF + c2];
            unsigned int p1 = *(const unsigned int*)&yb[(size_t)u1 * SF + c2];
            ax0 += BF2X(p0); ay0 += BF2Y(p0);
            ax1 += BF2X(p1); ay1 += BF2Y(p1);
        }
        if (i < e) {
            int u0 = src[i];
            unsigned int p0 = *(const unsigned int*)&yb[(size_t)u0 * SF + c2];
            ax0 += BF2X(p0); ay0 += BF2Y(p0);
        }

        float dv = dinv[g];
        float bx = bias[slab * SF + c2];
        float by = bias[slab * SF + c2 + 1];
        hx = fmaxf(fmaf(dv, ax0 + ax1, bx), 0.f);
        hy = fmaxf(fmaf(dv, ay0 + ay1, by), 0.f);

        if (WRITE_H) {
            unsigned int pk = (unsigned int)f2bf(hx) | ((unsigned int)f2bf(hy) << 16);
            __builtin_nontemporal_store(pk,
                (unsigned int*)&Hbf[((size_t)slab * n + g) * SF + c2]);
        }
    }

    if (!WRITE_H) {
        __shared__ float2 red[256];
        red[threadIdx.x] = make_float2(hx, hy);
        __syncthreads();
        for (int sft = 128; sft >= 8; sft >>= 1) {
            if (threadIdx.x < sft) {
                red[threadIdx.x].x += red[threadIdx.x + sft].x;
                red[threadIdx.x].y += red[threadIdx.x + sft].y;
            }
            __syncthreads();
        }
        if (threadIdx.x < 8) {
            atomicAdd(&gacc[slab * SF + threadIdx.x * 2],     red[threadIdx.x].x);
            atomicAdd(&gacc[slab * SF + threadIdx.x * 2 + 1], red[threadIdx.x].y);
        }
    }
}

// ---------------- Final: out[a] = sum_k (gacc[k]/N) * Wl[k][a] + bl[a] ----------------

__global__ void final_k(const float* __restrict__ gacc, const float* __restrict__ Wl,
                        const float* __restrict__ bl, float* __restrict__ out, float invN) {
    int a = threadIdx.x;
    if (a < 16) {
        float s = bl[a];
        for (int k = 0; k < 128; k++) s = fmaf(gacc[k] * invN, Wl[k * 16 + a], s);
        out[a] = s;
    }
}

extern "C" void kernel_launch(void* const* d_in, const int* in_sizes, int n_in,
                              void* d_out, int out_size, void* d_ws, size_t ws_size,
                              hipStream_t stream) {
    const float* x  = (const float*)d_in[0];
    const int*   ei = (const int*)d_in[1];
    const float* W1 = (const float*)d_in[2];
    const float* b1 = (const float*)d_in[3];
    const float* W2 = (const float*)d_in[4];
    const float* b2 = (const float*)d_in[5];
    const float* Wl = (const float*)d_in[6];
    const float* bl = (const float*)d_in[7];

    int N = in_sizes[0] / F;
    int E = in_sizes[1] / 2;
    const int* row = ei;
    const int* col = ei + E;

    char* ws = (char*)d_ws;
    size_t off = 0;
    auto alloc = [&](size_t bytes) -> void* {
        void* p = ws + off;
        off = (off + bytes + 255) & ~(size_t)255;
        return p;
    };
    int*            cnt    = (int*)           alloc((size_t)N * 4);
    int*            offs   = (int*)           alloc((size_t)(N + 1) * 4);
    int*            cursor = (int*)           alloc((size_t)N * 4);
    float*          dinv   = (float*)         alloc((size_t)N * 4);
    int*            bsum   = (int*)           alloc(1024 * 4);
    int*            srcb   = (int*)           alloc((size_t)E * 4);
    unsigned short* ybf    = (unsigned short*)alloc((size_t)N * F * 2);
    unsigned short* hbf    = (unsigned short*)alloc((size_t)N * F * 2);
    float*          gacc   = (float*)         alloc(128 * 4);

    hipMemsetAsync(cnt, 0, (size_t)N * 4, stream);
    hipMemsetAsync(gacc, 0, 128 * 4, stream);

    int NB = (N + 1023) / 1024;
    count_edges_k<<<(E / 4 + 255) / 256, 256, 0, stream>>>(col, cnt, E);
    scan1_k<<<NB, 1024, 0, stream>>>(cnt, offs, dinv, bsum, N);
    scan2_k<<<1, 128, 0, stream>>>(bsum, NB);
    scan3_k<<<(N + 1024) / 1024, 1024, 0, stream>>>(offs, cursor, bsum, N, E);
    fill_k<<<(E + 255) / 256, 256, 0, stream>>>(row, col, cursor, srcb, E);

    int GEMM_BLOCKS = (N + 63) / 64;
    int AGG_BLOCKS = 8 * ((N + 31) / 32);

    gemm_scale_k<0><<<GEMM_BLOCKS, 256, 0, stream>>>(x, W1, dinv, ybf, N);
    agg_k<1><<<AGG_BLOCKS, 256, 0, stream>>>(ybf, dinv, offs, srcb, b1, hbf, nullptr, N);
    gemm_scale_k<1><<<GEMM_BLOCKS, 256, 0, stream>>>(hbf, W2, dinv, ybf, N);
    agg_k<0><<<AGG_BLOCKS, 256, 0, stream>>>(ybf, dinv, offs, srcb, b2, nullptr, gacc, N);
    final_k<<<1, 64, 0, stream>>>(gacc, Wl, bl, (float*)d_out, 1.0f / (float)N);
}